// Round 3
// baseline (582.238 us; speedup 1.0000x reference)
//
#include <hip/hip_runtime.h>
#include <stdint.h>
#include <math.h>

// Problem dims
#define BS_  256
#define NSEQ 128
#define HH   512
#define DD   1152      // 2H + Z
#define VV   32000
#define BN_  (BS_*NSEQ)  // 32768

typedef float  f32x4  __attribute__((ext_vector_type(4)));
typedef __bf16 bf16x8 __attribute__((ext_vector_type(8)));

__device__ __forceinline__ f32x4 mfma16(bf16x8 a, bf16x8 b, f32x4 c) {
    return __builtin_amdgcn_mfma_f32_16x16x32_bf16(a, b, c, 0, 0, 0);
}

__device__ __forceinline__ bf16x8 pack8(f32x4 a, f32x4 b) {
    bf16x8 v;
    v[0] = (__bf16)a[0]; v[1] = (__bf16)a[1]; v[2] = (__bf16)a[2]; v[3] = (__bf16)a[3];
    v[4] = (__bf16)b[0]; v[5] = (__bf16)b[1]; v[6] = (__bf16)b[2]; v[7] = (__bf16)b[3];
    return v;
}

__device__ __forceinline__ float tanh_fast(float x) {
    float e = __expf(2.f * x);
    return 1.f - __fdividef(2.f, e + 1.f);
}

// async global->LDS, 16B per lane. LDS dest = wave-uniform base + lane*16.
__device__ __forceinline__ void gload16(const void* g, void* l) {
    __builtin_amdgcn_global_load_lds(
        (const __attribute__((address_space(1))) void*)g,
        (__attribute__((address_space(3))) void*)l, 16, 0, 0);
}

// ---------------------------------------------------------------------------
// cast f32 -> bf16, 8 elems/thread
// ---------------------------------------------------------------------------
__global__ __launch_bounds__(256) void k_cast(const float* __restrict__ src,
                                              __bf16* __restrict__ dst, int n8)
{
    int i = blockIdx.x * 256 + threadIdx.x;
    int stride = gridDim.x * 256;
    for (; i < n8; i += stride) {
        const f32x4* s = (const f32x4*)(src + (size_t)i * 8);
        f32x4 a = s[0], b = s[1];
        *(bf16x8*)(dst + (size_t)i * 8) = pack8(a, b);
    }
}

// ---------------------------------------------------------------------------
// k_plan: plan softmax (exact f32 dot over D) + prev_y -> y_ctx[0:512] copy.
// grid = 256 (one block per batch), 128 threads.
// ---------------------------------------------------------------------------
__global__ __launch_bounds__(128) void k_plan(
    const float* __restrict__ prev_h, const float* __restrict__ plan_W,
    const float* __restrict__ plan_b, const float* __restrict__ prev_y,
    float* __restrict__ y_ctx, float* __restrict__ plan_out)
{
    const int b = blockIdx.x;
    const int t = threadIdx.x;
    const int lane = t & 63, w = t >> 6;
    __shared__ float red[4];

    float p0 = 0.f, p1 = 0.f;
    for (int i = t; i < DD; i += 128) {
        float hv = prev_h[(size_t)b * DD + i];
        p0 += hv * plan_W[i];
        p1 += hv * plan_W[DD + i];
    }
    #pragma unroll
    for (int m = 1; m < 64; m <<= 1) { p0 += __shfl_xor(p0, m); p1 += __shfl_xor(p1, m); }
    if (lane == 0) { red[w] = p0; red[2 + w] = p1; }
    __syncthreads();
    if (t == 0) {
        float l0 = red[0] + red[1] + plan_b[0];
        float l1 = red[2] + red[3] + plan_b[1];
        float mm = fmaxf(l0, l1);
        float e0 = __expf(l0 - mm), e1 = __expf(l1 - mm);
        float ss = e0 + e1;
        plan_out[b * 2 + 0] = e0 / ss;
        plan_out[b * 2 + 1] = e1 / ss;
    }
    // prev_y copy into y_ctx[b][0:512]
    f32x4 v = *(const f32x4*)(prev_y + (size_t)b * 512 + t * 4);
    *(f32x4*)(y_ctx + (size_t)b * 1024 + t * 4) = v;
}

// ---------------------------------------------------------------------------
// k_attn3: fully fused attention for one (e,b) pair per block.
//  - stage enc[b] (128x512) once: f32 HBM -> bf16 LDS (XOR-swizzled)
//  - 4 col-phases x 16 K-steps of MFMA vs W1 (bf16, gload_lds dbuf 8KB tiles)
//  - fused tanh/vt row-reduction -> u[128] in LDS (LDS atomics)
//  - masked softmax in-block -> aw[128]
//  - ctx = aw @ enc  (from the LDS bf16 copy; enc read from HBM exactly once)
//  - y_ctx[b][512:1024] += plan[e] * ctx   (global atomics, 2 blocks/b)
// grid = 512 (e,b), 512 threads (8 waves: 2 row x 4 col), 1 block/CU (LDS).
// ---------------------------------------------------------------------------
__global__ __launch_bounds__(512, 1) void k_attn3(
    const float* __restrict__ enc_e, const float* __restrict__ enc_s,
    const __bf16* __restrict__ W1be, const __bf16* __restrict__ W1bs,
    const float* __restrict__ vte, const float* __restrict__ vts,
    const float* __restrict__ dt_e, const float* __restrict__ dt_s,
    const int* __restrict__ mask_e, const int* __restrict__ mask_s,
    const float* __restrict__ plan_out,
    float* __restrict__ y_ctx)
{
    const int L = blockIdx.x;      // 0..511
    const int e = L & 1;
    const int b = L >> 1;

    const float*  enc  = e ? enc_s : enc_e;
    const __bf16* W1   = e ? W1bs : W1be;
    const float*  vt   = e ? vts : vte;
    const float*  dt   = e ? dt_s : dt_e;
    const int*    mask = e ? mask_s : mask_e;

    __shared__ __bf16 Asm[128 * 512];     // 131072 B, enc tile bf16 swizzled
    __shared__ __bf16 Bsm[2][4096];       // 16384 B, W1 K-step dbuf
    __shared__ float  u_acc[128];
    __shared__ float  red[4];
    __shared__ float  ctxp[2][512];       // 4096 B

    const int t = threadIdx.x;
    const int w = t >> 6, wr = w >> 2, wcq = w & 3;
    const int lane = t & 63, g = lane >> 4, r = lane & 15;

    if (t < 128) u_acc[t] = 0.f;

    // ---- A-stage: enc[b] 128x512 f32 -> bf16 LDS, chunk-XOR swizzle ----
    {
        const float* Ag = enc + (size_t)b * (128 * 512);
        #pragma unroll
        for (int i = 0; i < 16; ++i) {
            int u = t + i * 512;                  // 32B-unit index (8 f32)
            int row = u >> 6, cc = u & 63;        // 64 units per row
            const f32x4* src = (const f32x4*)(Ag + row * 512 + cc * 8);
            f32x4 a0 = src[0], a1 = src[1];
            *(bf16x8*)&Asm[row * 512 + ((cc ^ (row & 7)) << 3)] = pack8(a0, a1);
        }
    }

    // ---- B staging addresses (per-thread global src, wave-uniform LDS dst)
    const int q_row = t >> 2, q_c = t & 3;
    const int q_cc  = q_c ^ ((q_row >> 1) & 3);
    const __bf16* Bsrc0 = W1 + q_row * 512 + q_cc * 8;
    const int BdstE = w * 512;                    // elems (wave-uniform)

    // prologue: stage phase0/kb0 into buf 0
    gload16(Bsrc0, &Bsm[0][BdstE]);

    f32x4 acc[4][2];
    float dv[2], vv[2];

    for (int ks = 0; ks < 64; ++ks) {
        const int ph = ks >> 4, kb = ks & 15;
        const int buf = ks & 1;
        __syncthreads();    // drains vmcnt: Bsm[buf] ready; A ready at ks=0
        if (ks + 1 < 64) {
            const int ph_n = (ks + 1) >> 4, kb_n = (ks + 1) & 15;
            gload16(Bsrc0 + ph_n * 65536 + kb_n * 32, &Bsm[buf ^ 1][BdstE]);
        }
        if (kb == 0) {
            #pragma unroll
            for (int i = 0; i < 4; ++i)
                #pragma unroll
                for (int j = 0; j < 2; ++j) acc[i][j] = (f32x4){0.f, 0.f, 0.f, 0.f};
            #pragma unroll
            for (int j = 0; j < 2; ++j) {
                int col = ph * 128 + wcq * 32 + j * 16 + r;
                dv[j] = dt[(size_t)b * 512 + col];
                vv[j] = vt[col];
            }
        }
        bf16x8 af[4], bfr[2];
        #pragma unroll
        for (int j = 0; j < 2; ++j) {
            int nb = wcq * 32 + j * 16 + r;
            bfr[j] = *(const bf16x8*)&Bsm[buf][nb * 32 + ((g ^ ((nb >> 1) & 3)) << 3)];
        }
        #pragma unroll
        for (int i = 0; i < 4; ++i) {
            int ra = wr * 64 + i * 16 + r;
            af[i] = *(const bf16x8*)&Asm[ra * 512 + (((kb * 4 + g) ^ (ra & 7)) << 3)];
        }
        #pragma unroll
        for (int i = 0; i < 4; ++i)
            #pragma unroll
            for (int j = 0; j < 2; ++j)
                acc[i][j] = mfma16(af[i], bfr[j], acc[i][j]);

        if (kb == 15) {
            // fused u-partial for this phase: s = sum_j vt*tanh(et+dt)
            #pragma unroll
            for (int i = 0; i < 4; ++i) {
                #pragma unroll
                for (int q = 0; q < 4; ++q) {
                    float s = vv[0] * tanh_fast(acc[i][0][q] + dv[0])
                            + vv[1] * tanh_fast(acc[i][1][q] + dv[1]);
                    #pragma unroll
                    for (int m = 1; m < 16; m <<= 1) s += __shfl_xor(s, m);
                    if (r == 0)
                        atomicAdd(&u_acc[wr * 64 + i * 16 + g * 4 + q], s);
                }
            }
        }
    }

    __syncthreads();   // u_acc complete

    // ---- masked softmax over 128 seq positions (waves 0-1) ----
    float exv = 0.f;
    if (t < 128) {
        float uv = u_acc[t];
        bool msk = mask[b * 128 + t] != 0;
        float val = msk ? -3.4e38f : uv;
        float mx = val;
        #pragma unroll
        for (int m = 1; m < 64; m <<= 1) mx = fmaxf(mx, __shfl_xor(mx, m));
        if (lane == 0) red[w] = mx;
        exv = msk ? 0.f : uv;   // carry uv; finish after max combine
    }
    __syncthreads();
    float smv = 0.f;
    if (t < 128) {
        float mx = fmaxf(red[0], red[1]);
        bool msk = mask[b * 128 + t] != 0;
        exv = msk ? 0.f : __expf(exv - mx);
        smv = exv;
        #pragma unroll
        for (int m = 1; m < 64; m <<= 1) smv += __shfl_xor(smv, m);
        if (lane == 0) red[2 + w] = smv;
    }
    __syncthreads();
    if (t < 128) {
        u_acc[t] = exv / (red[2] + red[3]);   // aw in-place
    }
    __syncthreads();

    // ---- ctx = aw @ enc (from LDS bf16 copy), waves 0-1 ----
    if (t < 128) {
        int cc = t & 63, rh = t >> 6;
        f32x4 s0 = {0.f, 0.f, 0.f, 0.f}, s1 = {0.f, 0.f, 0.f, 0.f};
        for (int row = rh * 64; row < rh * 64 + 64; ++row) {
            bf16x8 v = *(const bf16x8*)&Asm[row * 512 + ((cc ^ (row & 7)) << 3)];
            float a = u_acc[row];
            s0[0] += a * (float)v[0]; s0[1] += a * (float)v[1];
            s0[2] += a * (float)v[2]; s0[3] += a * (float)v[3];
            s1[0] += a * (float)v[4]; s1[1] += a * (float)v[5];
            s1[2] += a * (float)v[6]; s1[3] += a * (float)v[7];
        }
        *(f32x4*)&ctxp[rh][cc * 8]     = s0;
        *(f32x4*)&ctxp[rh][cc * 8 + 4] = s1;
    }
    __syncthreads();
    if (t < 128) {
        float pl = plan_out[b * 2 + e];
        f32x4 c0 = *(const f32x4*)&ctxp[0][t * 4];
        f32x4 c1 = *(const f32x4*)&ctxp[1][t * 4];
        float* dst = y_ctx + (size_t)b * 1024 + 512 + t * 4;
        atomicAdd(dst + 0, pl * (c0[0] + c1[0]));
        atomicAdd(dst + 1, pl * (c0[1] + c1[1]));
        atomicAdd(dst + 2, pl * (c0[2] + c1[2]));
        atomicAdd(dst + 3, pl * (c0[3] + c1[3]));
    }
}

// ---------------------------------------------------------------------------
// K6: vocab GEMM via global_load_lds staging.
// A = h_new (bf16 in LDS, produced by k_gru), B = Wout (f32 in LDS, cvt on read).
// grid = 512 XCD-swizzled (p>=250 idle).
// ---------------------------------------------------------------------------
__global__ __launch_bounds__(256) void k_vocab2(
    const __bf16* __restrict__ A,   // h_new bf16 [256][1152]
    const float* __restrict__ B,    // Wout f32 [32000][1152]
    const float* __restrict__ bias, float* __restrict__ C)
{
    const int L = blockIdx.x;
    const int p  = (L & 7) + ((L >> 4) << 3);   // col tile 0..255
    const int rr = (L >> 3) & 1;                // row tile 0..1
    if (p >= 250) return;
    const int rb = rr * 128, cb = p * 128;

    __shared__ __bf16 lA[2][4096];   // 128x32 bf16
    __shared__ float  lB[2][4096];   // 128x32 f32

    const int t = threadIdx.x;
    const int w = t >> 6, wr = w >> 1, wc = w & 1;
    const int lane = t & 63, g = lane >> 4, r = lane & 15;

    const __bf16* Ag = A + (size_t)rb * DD;
    const float*  Bg = B + (size_t)cb * DD;

    int aoff[2], boff[4], aldsb[2], bldsb[4];
    #pragma unroll
    for (int i = 0; i < 2; ++i) {                 // A: 512 chunks (bf16)
        int c = i * 256 + w * 64 + lane;
        int row = c >> 2, kc = c & 3;
        aoff[i]  = row * DD + ((kc ^ ((row >> 1) & 3)) << 3);
        aldsb[i] = (i * 256 + w * 64) << 3;
    }
    #pragma unroll
    for (int i = 0; i < 4; ++i) {                 // B: 1024 chunks (f32)
        int c = i * 256 + w * 64 + lane;
        int row = c >> 3, kc = c & 7;
        boff[i]  = row * DD + ((kc ^ (row & 7)) << 2);
        bldsb[i] = (i * 256 + w * 64) << 2;
    }

    f32x4 acc[4][4];
    #pragma unroll
    for (int i = 0; i < 4; ++i)
        #pragma unroll
        for (int j = 0; j < 4; ++j) acc[i][j] = (f32x4){0.f, 0.f, 0.f, 0.f};

    #pragma unroll
    for (int i = 0; i < 2; ++i) gload16(Ag + aoff[i], &lA[0][aldsb[i]]);
    #pragma unroll
    for (int i = 0; i < 4; ++i) gload16(Bg + boff[i], &lB[0][bldsb[i]]);

    for (int kb = 0; kb < 36; ++kb) {
        const int buf = kb & 1;
        __syncthreads();
        if (kb + 1 < 36) {
            const int k0 = (kb + 1) * 32;
            #pragma unroll
            for (int i = 0; i < 2; ++i) gload16(Ag + aoff[i] + k0, &lA[buf ^ 1][aldsb[i]]);
            #pragma unroll
            for (int i = 0; i < 4; ++i) gload16(Bg + boff[i] + k0, &lB[buf ^ 1][bldsb[i]]);
        }
        bf16x8 af[4], bfr[4];
        #pragma unroll
        for (int i = 0; i < 4; ++i) {
            int row = wr * 64 + i * 16 + r;
            af[i] = *(const bf16x8*)&lA[buf][row * 32 + ((g ^ ((row >> 1) & 3)) << 3)];
        }
        #pragma unroll
        for (int j = 0; j < 4; ++j) {
            int row = wc * 64 + j * 16 + r;
            int s = row & 7;
            f32x4 b0 = *(const f32x4*)&lB[buf][row * 32 + (((g << 1) ^ s) << 2)];
            f32x4 b1 = *(const f32x4*)&lB[buf][row * 32 + ((((g << 1) | 1) ^ s) << 2)];
            bfr[j] = pack8(b0, b1);
        }
        #pragma unroll
        for (int i = 0; i < 4; ++i)
            #pragma unroll
            for (int j = 0; j < 4; ++j)
                acc[i][j] = mfma16(af[i], bfr[j], acc[i][j]);
    }

    #pragma unroll
    for (int j = 0; j < 4; ++j) {
        const int col = cb + wc * 64 + j * 16 + r;
        const float bv = bias[col];
        #pragma unroll
        for (int i = 0; i < 4; ++i) {
            #pragma unroll
            for (int q = 0; q < 4; ++q) {
                const int row = rb + wr * 64 + i * 16 + g * 4 + q;
                C[(size_t)row * VV + col] = acc[i][j][q] + bv;
            }
        }
    }
}

// ---------------------------------------------------------------------------
// 128x128-tile reg-staged GEMM core (K4b).
// ---------------------------------------------------------------------------
__global__ __launch_bounds__(256) void k_tile128(
    const float* __restrict__ A, const float* __restrict__ B,
    const float* __restrict__ bias, float* __restrict__ C,
    int K, int ldc)
{
    const int rb = blockIdx.x * 128;
    const int cb = blockIdx.y * 128;
    const int t = threadIdx.x;
    const int w = t >> 6, wr = w >> 1, wc = w & 1;
    const int lane = t & 63, g = lane >> 4, r = lane & 15;
    const int s_row = t >> 1, s_h = t & 1;

    __shared__ bf16x8 sm[2][2][512];

    const float* Ap = A + (size_t)(rb + s_row) * K + s_h * 16;
    const float* Bp = B + (size_t)(cb + s_row) * K + s_h * 16;

    const int kg0 = 2 * s_h, kg1 = 2 * s_h + 1;
    const int swz0 = kg0 * 128 + ((s_row & 112) | ((s_row ^ (kg0 << 2)) & 15));
    const int swz1 = kg1 * 128 + ((s_row & 112) | ((s_row ^ (kg1 << 2)) & 15));

    int ai[4], bi[4];
    #pragma unroll
    for (int i = 0; i < 4; ++i) {
        ai[i] = g * 128 + wr * 64 + i * 16 + ((r ^ (g << 2)) & 15);
        bi[i] = g * 128 + wc * 64 + i * 16 + ((r ^ (g << 2)) & 15);
    }

    const int KS = K >> 5;
    f32x4 pa0 = ((const f32x4*)Ap)[0], pa1 = ((const f32x4*)Ap)[1],
          pa2 = ((const f32x4*)Ap)[2], pa3 = ((const f32x4*)Ap)[3];
    f32x4 pb0 = ((const f32x4*)Bp)[0], pb1 = ((const f32x4*)Bp)[1],
          pb2 = ((const f32x4*)Bp)[2], pb3 = ((const f32x4*)Bp)[3];

    f32x4 acc[4][4];
    #pragma unroll
    for (int i = 0; i < 4; ++i)
        #pragma unroll
        for (int j = 0; j < 4; ++j) acc[i][j] = (f32x4){0.f, 0.f, 0.f, 0.f};

    for (int kb = 0; kb < KS; ++kb) {
        const int buf = kb & 1;
        sm[buf][0][swz0] = pack8(pa0, pa1);
        sm[buf][0][swz1] = pack8(pa2, pa3);
        sm[buf][1][swz0] = pack8(pb0, pb1);
        sm[buf][1][swz1] = pack8(pb2, pb3);
        __syncthreads();
        if (kb + 1 < KS) {
            const float* a2 = Ap + (kb + 1) * 32;
            const float* b2 = Bp + (kb + 1) * 32;
            pa0 = ((const f32x4*)a2)[0]; pa1 = ((const f32x4*)a2)[1];
            pa2 = ((const f32x4*)a2)[2]; pa3 = ((const f32x4*)a2)[3];
            pb0 = ((const f32x4*)b2)[0]; pb1 = ((const f32x4*)b2)[1];
            pb2 = ((const f32x4*)b2)[2]; pb3 = ((const f32x4*)b2)[3];
        }
        bf16x8 af[4], bfr[4];
        #pragma unroll
        for (int i = 0; i < 4; ++i) af[i]  = sm[buf][0][ai[i]];
        #pragma unroll
        for (int j = 0; j < 4; ++j) bfr[j] = sm[buf][1][bi[j]];
        #pragma unroll
        for (int i = 0; i < 4; ++i)
            #pragma unroll
            for (int j = 0; j < 4; ++j)
                acc[i][j] = mfma16(af[i], bfr[j], acc[i][j]);
    }

    #pragma unroll
    for (int j = 0; j < 4; ++j) {
        const int col = cb + wc * 64 + j * 16 + r;
        const float bv = bias ? bias[col] : 0.f;
        #pragma unroll
        for (int i = 0; i < 4; ++i) {
            #pragma unroll
            for (int q = 0; q < 4; ++q) {
                const int row = rb + wr * 64 + i * 16 + g * 4 + q;
                C[(size_t)row * ldc + col] = acc[i][j][q] + bv;
            }
        }
    }
}

// ---------------------------------------------------------------------------
// K1: prev_h against virtual concat [W2e | W2s | w_hh], 64x64 tiles.
// ---------------------------------------------------------------------------
__global__ __launch_bounds__(256) void k_prevh(
    const float* __restrict__ prev_h, const float* __restrict__ W2e,
    const float* __restrict__ W2s, const float* __restrict__ w_hh,
    const float* __restrict__ b_hh,
    float* __restrict__ dt_e, float* __restrict__ dt_s, float* __restrict__ gh)
{
    const int cb = blockIdx.x * 64;
    const int rb = blockIdx.y * 64;
    const int t  = threadIdx.x;
    const int w = t >> 6, lane = t & 63, g = lane >> 4, r = lane & 15;
    const int s_row = t >> 2, s_kc = t & 3;
    const int K = DD;

    __shared__ bf16x8 sm[2][2][256];

    const float* Ap = prev_h + (size_t)(rb + s_row) * K + s_kc * 8;
    const float* Bp;
    {
        int brow = cb + s_row;
        if (cb < 512)        Bp = W2e + (size_t)brow * K;
        else if (cb < 1024)  Bp = W2s + (size_t)(brow - 512) * K;
        else                 Bp = w_hh + (size_t)(brow - 1024) * K;
        Bp += s_kc * 8;
    }

    const int KS = K >> 5;   // 36
    f32x4 pa0 = *(const f32x4*)Ap, pa1 = *(const f32x4*)(Ap + 4);
    f32x4 pb0 = *(const f32x4*)Bp, pb1 = *(const f32x4*)(Bp + 4);

    f32x4 acc[4] = {{0,0,0,0},{0,0,0,0},{0,0,0,0},{0,0,0,0}};

    for (int kb = 0; kb < KS; ++kb) {
        sm[kb & 1][0][s_kc * 64 + s_row] = pack8(pa0, pa1);
        sm[kb & 1][1][s_kc * 64 + s_row] = pack8(pb0, pb1);
        __syncthreads();
        if (kb + 1 < KS) {
            const float* a2 = Ap + (kb + 1) * 32;
            const float* b2 = Bp + (kb + 1) * 32;
            pa0 = *(const f32x4*)a2; pa1 = *(const f32x4*)(a2 + 4);
            pb0 = *(const f32x4*)b2; pb1 = *(const f32x4*)(b2 + 4);
        }
        bf16x8 af = sm[kb & 1][0][g * 64 + w * 16 + r];
        #pragma unroll
        for (int j = 0; j < 4; ++j) {
            bf16x8 bf = sm[kb & 1][1][g * 64 + j * 16 + r];
            acc[j] = mfma16(af, bf, acc[j]);
        }
    }

    #pragma unroll
    for (int j = 0; j < 4; ++j) {
        int col = cb + j * 16 + r;
        #pragma unroll
        for (int q = 0; q < 4; ++q) {
            int row = rb + w * 16 + g * 4 + q;
            float v = acc[j][q];
            if (cb < 512)       dt_e[(size_t)row * 512 + col] = v;
            else if (cb < 1024) dt_s[(size_t)row * 512 + (col - 512)] = v;
            else {
                int c0 = col - 1024;
                gh[(size_t)row * 3456 + c0] = v + b_hh[c0];
            }
        }
    }
}

// ---------------------------------------------------------------------------
// K4a: 64x64-tile GEMM (small x = y_ctx@Wc^T)
// ---------------------------------------------------------------------------
__global__ __launch_bounds__(256) void k_gemm_bias(
    const float* __restrict__ A, const float* __restrict__ B,
    const float* __restrict__ bias, float* __restrict__ C,
    int K, int ldc)
{
    const int cb = blockIdx.x * 64;
    const int rb = blockIdx.y * 64;
    const int t  = threadIdx.x;
    const int w = t >> 6, lane = t & 63, g = lane >> 4, r = lane & 15;
    const int s_row = t >> 2, s_kc = t & 3;

    __shared__ bf16x8 sm[2][2][256];

    const float* Ap = A + (size_t)(rb + s_row) * K + s_kc * 8;
    const float* Bp = B + (size_t)(cb + s_row) * K + s_kc * 8;

    const int KS = K >> 5;
    f32x4 pa0 = *(const f32x4*)Ap, pa1 = *(const f32x4*)(Ap + 4);
    f32x4 pb0 = *(const f32x4*)Bp, pb1 = *(const f32x4*)(Bp + 4);

    f32x4 acc[4] = {{0,0,0,0},{0,0,0,0},{0,0,0,0},{0,0,0,0}};

    for (int kb = 0; kb < KS; ++kb) {
        sm[kb & 1][0][s_kc * 64 + s_row] = pack8(pa0, pa1);
        sm[kb & 1][1][s_kc * 64 + s_row] = pack8(pb0, pb1);
        __syncthreads();
        if (kb + 1 < KS) {
            const float* a2 = Ap + (kb + 1) * 32;
            const float* b2 = Bp + (kb + 1) * 32;
            pa0 = *(const f32x4*)a2; pa1 = *(const f32x4*)(a2 + 4);
            pb0 = *(const f32x4*)b2; pb1 = *(const f32x4*)(b2 + 4);
        }
        bf16x8 af = sm[kb & 1][0][g * 64 + w * 16 + r];
        #pragma unroll
        for (int j = 0; j < 4; ++j) {
            bf16x8 bf = sm[kb & 1][1][g * 64 + j * 16 + r];
            acc[j] = mfma16(af, bf, acc[j]);
        }
    }
    #pragma unroll
    for (int j = 0; j < 4; ++j) {
        int col = cb + j * 16 + r;
        float bv = bias ? bias[col] : 0.f;
        #pragma unroll
        for (int q = 0; q < 4; ++q) {
            int row = rb + w * 16 + g * 4 + q;
            C[(size_t)row * ldc + col] = acc[j][q] + bv;
        }
    }
}

// ---------------------------------------------------------------------------
// K5: GRU gates + bf16 copy of h_new for vocab GEMM. grid=(3, BS), 384 thr.
// ---------------------------------------------------------------------------
__global__ __launch_bounds__(384) void k_gru(
    const float* __restrict__ gx, const float* __restrict__ gh,
    const float* __restrict__ prev_h, float* __restrict__ h_new,
    float* __restrict__ out_hidden, __bf16* __restrict__ h_new_bf)
{
    int d = blockIdx.x * 384 + threadIdx.x;   // 0..1151
    int b = blockIdx.y;
    size_t o3 = (size_t)b * 3456;
    float xr = gx[o3 + d], xz = gx[o3 + 1152 + d], xn = gx[o3 + 2304 + d];
    float hr = gh[o3 + d], hz = gh[o3 + 1152 + d], hn = gh[o3 + 2304 + d];
    float rr = 1.f / (1.f + __expf(-(xr + hr)));
    float zz = 1.f / (1.f + __expf(-(xz + hz)));
    float nv = tanhf(xn + rr * hn);
    float hv = (1.f - zz) * nv + zz * prev_h[(size_t)b * DD + d];
    h_new[(size_t)b * DD + d] = hv;
    out_hidden[(size_t)b * DD + d] = hv;
    h_new_bf[(size_t)b * DD + d] = (__bf16)hv;
}

// ---------------------------------------------------------------------------
extern "C" void kernel_launch(void* const* d_in, const int* in_sizes, int n_in,
                              void* d_out, int out_size, void* d_ws, size_t ws_size,
                              hipStream_t stream)
{
    const float* prev_y = (const float*)d_in[0];
    const float* prev_h = (const float*)d_in[1];
    const float* enc_e  = (const float*)d_in[2];
    const float* enc_s  = (const float*)d_in[3];
    const int*   mask_e = (const int*)d_in[5];
    const int*   mask_s = (const int*)d_in[6];
    const float* W1e    = (const float*)d_in[7];
    const float* W2e    = (const float*)d_in[8];
    const float* vte    = (const float*)d_in[9];
    const float* W1s    = (const float*)d_in[10];
    const float* W2s    = (const float*)d_in[11];
    const float* vts    = (const float*)d_in[12];
    const float* plan_W = (const float*)d_in[13];
    const float* plan_b = (const float*)d_in[14];
    const float* Wc     = (const float*)d_in[15];
    const float* bc     = (const float*)d_in[16];
    const float* w_ih   = (const float*)d_in[17];
    const float* w_hh   = (const float*)d_in[18];
    const float* b_ih   = (const float*)d_in[19];
    const float* b_hh   = (const float*)d_in[20];
    const float* Wout   = (const float*)d_in[21];
    const float* bout   = (const float*)d_in[22];

    float* out = (float*)d_out;
    float* ws  = (float*)d_ws;

    // workspace layout (lifetime-based aliasing):
    float* gh     = ws;                    // 884736   (K1 -> K5)
    float* big2   = ws + 884736;           // 884736:  dt_e|dt_s (K1->K2) then gx (K4b->K5)
    float* upxx   = big2 + 884736;         // 262144:  xx (K4a->K4b)
    float* y_ctx  = upxx + 262144;         // 262144   (plan/attn3 -> K4a)
    float* h_new  = y_ctx + 262144;        // 294912   (K5, f32 copy)
    __bf16* W1be  = (__bf16*)(h_new + 294912);       // 262144 bf16
    __bf16* W1bs  = W1be + 262144;                   // 262144 bf16
    __bf16* hnbf  = W1bs + 262144;                   // 294912 bf16

    float* dt_e  = big2;
    float* dt_s  = big2 + 131072;
    float* gx    = big2;
    float* xx    = upxx;

    float* dec_out  = out;                 // 256*32000
    float* dec_hid  = out + 8192000;       // 256*1152
    float* plan_out = out + 8486912;       // 256*2

    // zero y_ctx (ctx accumulated via atomics)
    hipMemsetAsync(y_ctx, 0, 262144 * sizeof(float), stream);

    // W1 casts (tiny, no deps)
    k_cast<<<dim3(128), 256, 0, stream>>>(W1e, W1be, 32768);
    k_cast<<<dim3(128), 256, 0, stream>>>(W1s, W1bs, 32768);

    // plan softmax + prev_y copy (needed by k_attn3's ctx accumulation)
    k_plan<<<dim3(BS_), 128, 0, stream>>>(prev_h, plan_W, plan_b, prev_y,
                                          y_ctx, plan_out);

    // K1: dt_e, dt_s, gh
    k_prevh<<<dim3(70, 4), 256, 0, stream>>>(prev_h, W2e, W2s, w_hh, b_hh,
                                             dt_e, dt_s, gh);

    // K2+K3 fused: attention logits + softmax + ctx (enc single-pass)
    k_attn3<<<dim3(512), 512, 0, stream>>>(
        enc_e, enc_s, W1be, W1bs, vte, vts, dt_e, dt_s,
        mask_e, mask_s, plan_out, y_ctx);

    // K4a: x = y_ctx @ Wc^T + bc
    k_gemm_bias<<<dim3(8, 4), 256, 0, stream>>>(y_ctx, Wc, bc, xx, 1024, 512);
    // K4b: gx = x @ w_ih^T + b_ih
    k_tile128<<<dim3(2, 27), 256, 0, stream>>>(xx, w_ih, b_ih, gx, 512, 3456);

    // K5: GRU (+ bf16 h_new)
    k_gru<<<dim3(3, BS_), 384, 0, stream>>>(gx, gh, prev_h, h_new, dec_hid, hnbf);

    // K6: dec_output = h_new @ Wout^T + bout (gload_lds core, f32 Wout in LDS)
    k_vocab2<<<dim3(512), 256, 0, stream>>>(hnbf, Wout, bout, dec_out);
}